// Round 4
// baseline (212.661 us; speedup 1.0000x reference)
//
#include <hip/hip_runtime.h>

// fp16 compute throughout (fp16 MFMA = bf16 rate on gfx950, 8x lower rounding error).
typedef _Float16 f16;
typedef __attribute__((ext_vector_type(8))) _Float16 f16x8;
typedef __attribute__((ext_vector_type(4))) _Float16 f16x4;
typedef __attribute__((ext_vector_type(4))) float   f32x4;

typedef unsigned int u32;
typedef __attribute__((address_space(1))) const u32 gu32;
typedef __attribute__((address_space(3))) u32 lu32;

// async global->LDS, 16B per lane; LDS dest = wave-uniform base + lane*16
__device__ inline void gll16(const void* g, void* l) {
  __builtin_amdgcn_global_load_lds((gu32*)g, (lu32*)l, 16, 0, 0);
}

// ---------------- f32 -> f16 elementwise convert (x) ----------------
__global__ void cvt_f32_f16(const float* __restrict__ in, f16* __restrict__ out, int n4) {
  int i = blockIdx.x * blockDim.x + threadIdx.x;
  if (i < n4) {
    float4 v = ((const float4*)in)[i];
    f16x4 r = { (f16)v.x, (f16)v.y, (f16)v.z, (f16)v.w };
    ((f16x4*)out)[i] = r;
  }
}

// ---------------- fused f32->f16 transpose of all three weight matrices ----------------
__global__ void transpose3(const float* __restrict__ Wq, const float* __restrict__ Wkv,
                           const float* __restrict__ Wo, f16* __restrict__ WqkvT,
                           f16* __restrict__ WoT) {
  __shared__ float tile[32][33];
  int z = blockIdx.z;
  const float* src; f16* dst; int W;
  if (z == 0)      { src = Wq;  dst = WqkvT;                       W = 1024; }
  else if (z == 1) { src = Wkv; dst = WqkvT + (size_t)1024 * 1024; W = 2048; }
  else             { src = Wo;  dst = WoT;                         W = 1024; }
  int c0 = blockIdx.x * 32, r0 = blockIdx.y * 32;
  if (c0 >= W) return;
  int tx = threadIdx.x, ty = threadIdx.y;   // block (32,8)
  for (int i = 0; i < 4; i++)
    tile[ty + i * 8][tx] = src[(size_t)(r0 + ty + i * 8) * W + c0 + tx];
  __syncthreads();
  for (int i = 0; i < 4; i++)
    dst[(size_t)(c0 + ty + i * 8) * 1024 + r0 + tx] = (f16)tile[tx][ty + i * 8];
}

// ---------------- GEMM1: C[M,3072] = A(M,1024) * Bt(3072,1024)^T ----------------
__global__ __launch_bounds__(256) void gemm1(
    const f16* __restrict__ A, const f16* __restrict__ Bt,
    f16* __restrict__ qb, f16* __restrict__ kb, f16* __restrict__ vtb) {
  const int K = 1024;
  __shared__ f16 As[128 * 32];
  __shared__ f16 Bs[128 * 32];
  int tid = threadIdx.x;
  int wave = tid >> 6, lane = tid & 63, quad = lane >> 4, l16 = lane & 15;
  int m0 = blockIdx.y * 128, n0 = blockIdx.x * 128;
  int wr = (wave >> 1) * 64, wc = (wave & 1) * 64;

  f32x4 acc[4][4] = {};

  int gA = (((lane & 3) ^ ((lane >> 3) & 3))) * 8;   // swizzled source k-chunk
  const f16* Ag = A  + (size_t)(m0 + wave * 32 + (lane >> 2)) * K + gA;
  const f16* Bg = Bt + (size_t)(n0 + wave * 32 + (lane >> 2)) * K + gA;
  f16* Asw = As + wave * 1024;
  f16* Bsw = Bs + wave * 1024;
  int rsz = (l16 >> 1) & 3;

  for (int k0 = 0; k0 < K; k0 += 32) {
    gll16(Ag + k0, Asw);
    gll16(Ag + (size_t)16 * K + k0, Asw + 512);
    gll16(Bg + k0, Bsw);
    gll16(Bg + (size_t)16 * K + k0, Bsw + 512);
    __syncthreads();
    f16x8 af[4], bf[4];
    for (int mt = 0; mt < 4; mt++)
      af[mt] = *(const f16x8*)&As[(wr + mt * 16 + l16) * 32 + ((quad ^ rsz) << 3)];
    for (int nt = 0; nt < 4; nt++)
      bf[nt] = *(const f16x8*)&Bs[(wc + nt * 16 + l16) * 32 + ((quad ^ rsz) << 3)];
    for (int mt = 0; mt < 4; mt++)
      for (int nt = 0; nt < 4; nt++)
        acc[mt][nt] = __builtin_amdgcn_mfma_f32_16x16x32_f16(af[mt], bf[nt], acc[mt][nt], 0, 0, 0);
    __syncthreads();
  }

  if (n0 < 2048) {
    for (int mt = 0; mt < 4; mt++)
      for (int nt = 0; nt < 4; nt++)
        for (int r = 0; r < 4; r++) {
          int row = m0 + wr + mt * 16 + quad * 4 + r;
          int col = n0 + wc + nt * 16 + l16;
          float v = acc[mt][nt][r];
          int b = row >> 11, n = row & 2047;
          if (col < 1024) {
            // fold attention scale AND log2(e): softmax runs in log2 domain
            qb[(((size_t)b * 16 + (col >> 6)) * 2048 + n) * 64 + (col & 63)] =
                (f16)(v * 0.1803368801111137f);  // 0.125 * log2(e)
          } else {
            int c = col - 1024;
            kb[(((size_t)b * 16 + (c >> 6)) * 2048 + n) * 64 + (c & 63)] = (f16)v;
          }
        }
  } else {
    // v: blocked [bh][jblk][d][jin], packed f16x4 along n (jin)
    for (int mt = 0; mt < 4; mt++)
      for (int nt = 0; nt < 4; nt++) {
        int rb = m0 + wr + mt * 16 + quad * 4;
        int c  = n0 + wc + nt * 16 + l16 - 2048;
        int b = rb >> 11, n = rb & 2047;
        f16x4 pk = { (f16)acc[mt][nt][0], (f16)acc[mt][nt][1],
                     (f16)acc[mt][nt][2], (f16)acc[mt][nt][3] };
        size_t idx = (((size_t)(b * 16 + (c >> 6)) * 32 + (n >> 6)) * 64 + (c & 63)) * 64 + (n & 63);
        *(f16x4*)&vtb[idx] = pk;
      }
  }
}

// ---------------- GEMM2: out[M,1024] = A(M,1024)*Bt(1024,1024)^T + bo ----------------
__global__ __launch_bounds__(256) void gemm2(
    const f16* __restrict__ A, const f16* __restrict__ Bt,
    const float* __restrict__ bo, float* __restrict__ outf) {
  const int K = 1024;
  __shared__ f16 As[128 * 32];
  __shared__ f16 Bs[64 * 32];
  int tid = threadIdx.x;
  int wave = tid >> 6, lane = tid & 63, quad = lane >> 4, l16 = lane & 15;
  int m0 = blockIdx.y * 128, n0 = blockIdx.x * 64;
  int wr = (wave >> 1) * 64, wc = (wave & 1) * 32;

  f32x4 acc[4][2] = {};

  int gA = (((lane & 3) ^ ((lane >> 3) & 3))) * 8;
  const f16* Ag = A  + (size_t)(m0 + wave * 32 + (lane >> 2)) * K + gA;
  const f16* Bg = Bt + (size_t)(n0 + wave * 16 + (lane >> 2)) * K + gA;
  f16* Asw = As + wave * 1024;
  f16* Bsw = Bs + wave * 512;
  int rsz = (l16 >> 1) & 3;

  for (int k0 = 0; k0 < K; k0 += 32) {
    gll16(Ag + k0, Asw);
    gll16(Ag + (size_t)16 * K + k0, Asw + 512);
    gll16(Bg + k0, Bsw);
    __syncthreads();
    f16x8 af[4], bf[2];
    for (int mt = 0; mt < 4; mt++)
      af[mt] = *(const f16x8*)&As[(wr + mt * 16 + l16) * 32 + ((quad ^ rsz) << 3)];
    for (int nt = 0; nt < 2; nt++)
      bf[nt] = *(const f16x8*)&Bs[(wc + nt * 16 + l16) * 32 + ((quad ^ rsz) << 3)];
    for (int mt = 0; mt < 4; mt++)
      for (int nt = 0; nt < 2; nt++)
        acc[mt][nt] = __builtin_amdgcn_mfma_f32_16x16x32_f16(af[mt], bf[nt], acc[mt][nt], 0, 0, 0);
    __syncthreads();
  }

  for (int mt = 0; mt < 4; mt++)
    for (int nt = 0; nt < 2; nt++)
      for (int r = 0; r < 4; r++) {
        int row = m0 + wr + mt * 16 + quad * 4 + r;
        int col = n0 + wc + nt * 16 + l16;
        outf[(size_t)row * 1024 + col] = acc[mt][nt][r] + bo[col];
      }
}

// ---------------- fused causal attention: barrier-free, transposed-S ----------------
// Each WAVE is an independent 32-row q-tile. K/V MFMA fragments are loaded directly
// from global (L2-resident: per-XCD working set 2MB via bh->XCD affinity), register
// double-buffered one 64-j tile ahead -> fine-grained vmcnt, NO __syncthreads at all.
// Per-wave-private LDS only for the P (C->A layout) round-trip, lgkmcnt-synced.
// t/63-t pairing across grid halves balances per-CU work exactly (blocks b and b+256
// share a CU under round-robin dispatch). gm (unmasked row-max) is only a softmax
// shift; cancels except via eps (<=3e-5) -> causal-only online softmax.
__global__ __launch_bounds__(256) void attn(
    const f16* __restrict__ qb, const f16* __restrict__ kb,
    const f16* __restrict__ vtb, f16* __restrict__ ob) {
  __shared__ f16 Ps[4][16 * 64];     // per-wave private, XOR-swizzled rows
  int tid = threadIdx.x, wave = tid >> 6, lane = tid & 63, quad = lane >> 4, l16 = lane & 15;
  int l7 = l16 & 7;

  int bx = blockIdx.x;               // gridDim = 512
  int half = bx >> 8, r = bx & 255;
  int bh = ((r & 7) << 2) | ((r >> 3) & 3);   // xcd = bx%8 -> same bh pinned to one XCD
  int s  = ((r >> 5) << 2) | wave;            // 0..31
  int t  = half ? 63 - s : s;                 // 0..63: 32-row tile index
  int wq0 = t * 32;
  int b = bh >> 4, h = bh & 15;

  const f16* Q  = qb  + (size_t)bh * 2048 * 64;
  const f16* Kg = kb  + (size_t)bh * 2048 * 64;
  const f16* Vg = vtb + (size_t)bh * 32 * 4096;   // blocked [jblk][d][64j]

  f16x8 qf[2][2];
  for (int mt = 0; mt < 2; mt++)
    for (int ks = 0; ks < 2; ks++)
      qf[mt][ks] = *(const f16x8*)&Q[(size_t)(wq0 + mt * 16 + l16) * 64 + ks * 32 + quad * 8];

  f32x4 acc[2][4] = {};
  float mrow[2] = { -1e30f, -1e30f }, lrow[2] = { 0.f, 0.f };

  int fragoff = (l16 * 64) + quad * 8;   // row l16, chunk quad (f16 elems)

  auto loadKV = [&](f16x8 (&kf)[4][2], f16x8 (&vf)[4][2], int j0) {
    const f16* kp = Kg + (size_t)j0 * 64;
    const f16* vp = Vg + (size_t)(j0 >> 6) * 4096;
    for (int nt = 0; nt < 4; nt++)
      for (int ks = 0; ks < 2; ks++) {
        int off = nt * 1024 + ks * 32 + fragoff;
        kf[nt][ks] = *(const f16x8*)&kp[off];
        vf[nt][ks] = *(const f16x8*)&vp[off];
      }
  };

  auto compute = [&](const f16x8 (&kf)[4][2], const f16x8 (&vf)[4][2], int j0) {
    for (int mt = 0; mt < 2; mt++) {
      int im = wq0 + mt * 16;
      int i  = im + l16;                 // this lane's q-row

      // S^T tiles: lane = (j = j0+nt*16+quad*4+r, i = l16)
      f32x4 st[4];
      for (int nt = 0; nt < 4; nt++) {
        f32x4 z = {0.f, 0.f, 0.f, 0.f};
        z = __builtin_amdgcn_mfma_f32_16x16x32_f16(kf[nt][0], qf[mt][0], z, 0, 0, 0);
        z = __builtin_amdgcn_mfma_f32_16x16x32_f16(kf[nt][1], qf[mt][1], z, 0, 0, 0);
        st[nt] = z;
      }
      if (j0 + 63 > im) {                // partial block: causal mask
        for (int nt = 0; nt < 4; nt++) {
          int jc = j0 + nt * 16 + quad * 4;
          for (int rr = 0; rr < 4; rr++)
            st[nt][rr] = (jc + rr <= i) ? st[nt][rr] : -1e30f;
        }
      }
      // row max: reg tree + 2 cross-quad shuffles
      float v = fmaxf(fmaxf(fmaxf(st[0][0], st[0][1]), fmaxf(st[0][2], st[0][3])),
                      fmaxf(fmaxf(st[1][0], st[1][1]), fmaxf(st[1][2], st[1][3])));
      v = fmaxf(v, fmaxf(fmaxf(fmaxf(st[2][0], st[2][1]), fmaxf(st[2][2], st[2][3])),
                         fmaxf(fmaxf(st[3][0], st[3][1]), fmaxf(st[3][2], st[3][3]))));
      v = fmaxf(v, __shfl_xor(v, 16));
      v = fmaxf(v, __shfl_xor(v, 32));
      float mold = mrow[mt];
      float mn = fmaxf(mold, v);
      mrow[mt] = mn;
      if (__any(mn > mold)) {            // wave-uniform: skip rescale when max unchanged
        float al = __builtin_amdgcn_exp2f(mold - mn);
        lrow[mt] *= al;
        for (int nt = 0; nt < 4; nt++)
          for (int rr = 0; rr < 4; rr++) acc[mt][nt][rr] *= al;
      }
      // p = 2^(s-m) (masked entries underflow to 0); packed swizzled write to Ps[i][j]
      float psum = 0.f;
      for (int nt = 0; nt < 4; nt++) {
        f16x4 pk;
        for (int rr = 0; rr < 4; rr++) {
          float p = __builtin_amdgcn_exp2f(st[nt][rr] - mn);
          psum += p;
          pk[rr] = (f16)p;
        }
        int pos = (nt * 2 + (quad >> 1)) ^ l7;
        *(f16x4*)((char*)&Ps[wave][0] + l16 * 128 + pos * 16 + (quad & 1) * 8) = pk;
      }
      psum += __shfl_xor(psum, 16);
      psum += __shfl_xor(psum, 32);
      lrow[mt] += psum;

      // O^T += V^T P^T
      for (int ks = 0; ks < 2; ks++) {
        f16x8 pf = *(const f16x8*)((char*)&Ps[wave][0] + l16 * 128 + (((ks * 4 + quad) ^ l7) * 16));
        for (int nt = 0; nt < 4; nt++)
          acc[mt][nt] = __builtin_amdgcn_mfma_f32_16x16x32_f16(vf[nt][ks], pf, acc[mt][nt], 0, 0, 0);
      }
    }
  };

  // register-double-buffered j-loop, no barriers
  int jend = wq0 + 32;
  f16x8 kfA[4][2], vfA[4][2], kfB[4][2], vfB[4][2];
  loadKV(kfA, vfA, 0);
  for (int j0 = 0;;) {
    if (j0 + 64 < jend) loadKV(kfB, vfB, j0 + 64);
    compute(kfA, vfA, j0);
    j0 += 64;
    if (j0 >= jend) break;
    if (j0 + 64 < jend) loadKV(kfA, vfA, j0 + 64);
    compute(kfB, vfB, j0);
    j0 += 64;
    if (j0 >= jend) break;
  }

  // out = acc / (l + eps); acc lane = (d = nt*16+quad*4+r, i = l16) -> f16x4 along d
  for (int mt = 0; mt < 2; mt++) {
    float inv = 1.f / (lrow[mt] + 1e-8f);
    int n = wq0 + mt * 16 + l16;
    for (int nt = 0; nt < 4; nt++) {
      f16x4 o = { (f16)(acc[mt][nt][0] * inv), (f16)(acc[mt][nt][1] * inv),
                  (f16)(acc[mt][nt][2] * inv), (f16)(acc[mt][nt][3] * inv) };
      *(f16x4*)&ob[((size_t)b * 2048 + n) * 1024 + h * 64 + nt * 16 + quad * 4] = o;
    }
  }
}

extern "C" void kernel_launch(void* const* d_in, const int* in_sizes, int n_in,
                              void* d_out, int out_size, void* d_ws, size_t ws_size,
                              hipStream_t stream) {
  const float* x   = (const float*)d_in[0];   // (2,2048,1024)
  const float* Wq  = (const float*)d_in[1];   // (1024,1024)
  const float* Wkv = (const float*)d_in[2];   // (1024,2048)
  const float* Wo  = (const float*)d_in[3];   // (1024,1024)
  const float* bo  = (const float*)d_in[4];   // (1024,)
  float* out = (float*)d_out;                 // (2,2048,1024) f32

  char* ws = (char*)d_ws;
  f16* xb    = (f16*)ws;  ws += (size_t)4096 * 1024 * 2;
  f16* WqkvT = (f16*)ws;  ws += (size_t)3072 * 1024 * 2;
  f16* WoT   = (f16*)ws;  ws += (size_t)1024 * 1024 * 2;
  f16* qb    = (f16*)ws;  ws += (size_t)32 * 2048 * 64 * 2;
  f16* kb    = (f16*)ws;  ws += (size_t)32 * 2048 * 64 * 2;
  f16* vtb   = (f16*)ws;  ws += (size_t)32 * 64 * 2048 * 2;
  f16* ob    = xb;  // xb dead after GEMM1; reuse

  cvt_f32_f16<<<dim3(4096), 256, 0, stream>>>(x, xb, 4096 * 1024 / 4);
  transpose3<<<dim3(64, 32, 3), dim3(32, 8), 0, stream>>>(Wq, Wkv, Wo, WqkvT, WoT);

  gemm1<<<dim3(24, 32), 256, 0, stream>>>(xb, WqkvT, qb, kb, vtb);
  attn<<<dim3(512), 256, 0, stream>>>(qb, kb, vtb, ob);
  gemm2<<<dim3(16, 32), 256, 0, stream>>>(ob, WoT, bo, out);
}

// Round 5
// 180.434 us; speedup vs baseline: 1.1786x; 1.1786x over previous
//
#include <hip/hip_runtime.h>

// fp16 compute throughout (fp16 MFMA = bf16 rate on gfx950, 8x lower rounding error).
typedef _Float16 f16;
typedef __attribute__((ext_vector_type(8))) _Float16 f16x8;
typedef __attribute__((ext_vector_type(4))) _Float16 f16x4;
typedef __attribute__((ext_vector_type(4))) float   f32x4;

typedef unsigned int u32;
typedef __attribute__((address_space(1))) const u32 gu32;
typedef __attribute__((address_space(3))) u32 lu32;

// async global->LDS, 16B per lane; LDS dest = wave-uniform base + lane*16
__device__ inline void gll16(const void* g, void* l) {
  __builtin_amdgcn_global_load_lds((gu32*)g, (lu32*)l, 16, 0, 0);
}

// ---------------- prep: weight transposes (z<3) + x f32->f16 convert (z=3) ----------------
__global__ void prep(const float* __restrict__ Wq, const float* __restrict__ Wkv,
                     const float* __restrict__ Wo, const float* __restrict__ x,
                     f16* __restrict__ WqkvT, f16* __restrict__ WoT, f16* __restrict__ xb) {
  __shared__ float tile[32][33];
  int z = blockIdx.z;
  int tx = threadIdx.x, ty = threadIdx.y;   // block (32,8)
  if (z == 3) {
    // cvt: 2048 blocks * 256 threads * 2 float4 = 4096*1024 elems exactly
    size_t flat = ((size_t)(blockIdx.y * 64 + blockIdx.x) * 256 + ty * 32 + tx) * 2;
    for (int i = 0; i < 2; i++) {
      float4 v = ((const float4*)x)[flat + i];
      f16x4 r = { (f16)v.x, (f16)v.y, (f16)v.z, (f16)v.w };
      ((f16x4*)xb)[flat + i] = r;
    }
    return;
  }
  const float* src; f16* dst; int W;
  if (z == 0)      { src = Wq;  dst = WqkvT;                       W = 1024; }
  else if (z == 1) { src = Wkv; dst = WqkvT + (size_t)1024 * 1024; W = 2048; }
  else             { src = Wo;  dst = WoT;                         W = 1024; }
  int c0 = blockIdx.x * 32, r0 = blockIdx.y * 32;
  if (c0 >= W) return;
  for (int i = 0; i < 4; i++)
    tile[ty + i * 8][tx] = src[(size_t)(r0 + ty + i * 8) * W + c0 + tx];
  __syncthreads();
  for (int i = 0; i < 4; i++)
    dst[(size_t)(c0 + ty + i * 8) * 1024 + r0 + tx] = (f16)tile[tx][ty + i * 8];
}

// ---------------- GEMM1: C[M,3072] = A(M,1024) * Bt(3072,1024)^T ----------------
__global__ __launch_bounds__(256) void gemm1(
    const f16* __restrict__ A, const f16* __restrict__ Bt,
    f16* __restrict__ qb, f16* __restrict__ kb, f16* __restrict__ vtb) {
  const int K = 1024;
  __shared__ f16 As[128 * 32];
  __shared__ f16 Bs[128 * 32];
  int tid = threadIdx.x;
  int wave = tid >> 6, lane = tid & 63, quad = lane >> 4, l16 = lane & 15;
  int m0 = blockIdx.y * 128, n0 = blockIdx.x * 128;
  int wr = (wave >> 1) * 64, wc = (wave & 1) * 64;

  f32x4 acc[4][4] = {};

  int gA = (((lane & 3) ^ ((lane >> 3) & 3))) * 8;   // swizzled source k-chunk
  const f16* Ag = A  + (size_t)(m0 + wave * 32 + (lane >> 2)) * K + gA;
  const f16* Bg = Bt + (size_t)(n0 + wave * 32 + (lane >> 2)) * K + gA;
  f16* Asw = As + wave * 1024;
  f16* Bsw = Bs + wave * 1024;
  int rsz = (l16 >> 1) & 3;

  for (int k0 = 0; k0 < K; k0 += 32) {
    gll16(Ag + k0, Asw);
    gll16(Ag + (size_t)16 * K + k0, Asw + 512);
    gll16(Bg + k0, Bsw);
    gll16(Bg + (size_t)16 * K + k0, Bsw + 512);
    __syncthreads();
    f16x8 af[4], bf[4];
    for (int mt = 0; mt < 4; mt++)
      af[mt] = *(const f16x8*)&As[(wr + mt * 16 + l16) * 32 + ((quad ^ rsz) << 3)];
    for (int nt = 0; nt < 4; nt++)
      bf[nt] = *(const f16x8*)&Bs[(wc + nt * 16 + l16) * 32 + ((quad ^ rsz) << 3)];
    for (int mt = 0; mt < 4; mt++)
      for (int nt = 0; nt < 4; nt++)
        acc[mt][nt] = __builtin_amdgcn_mfma_f32_16x16x32_f16(af[mt], bf[nt], acc[mt][nt], 0, 0, 0);
    __syncthreads();
  }

  if (n0 < 2048) {
    for (int mt = 0; mt < 4; mt++)
      for (int nt = 0; nt < 4; nt++)
        for (int r = 0; r < 4; r++) {
          int row = m0 + wr + mt * 16 + quad * 4 + r;
          int col = n0 + wc + nt * 16 + l16;
          float v = acc[mt][nt][r];
          int b = row >> 11, n = row & 2047;
          if (col < 1024) {
            // fold attention scale AND log2(e): softmax runs in log2 domain
            qb[(((size_t)b * 16 + (col >> 6)) * 2048 + n) * 64 + (col & 63)] =
                (f16)(v * 0.1803368801111137f);  // 0.125 * log2(e)
          } else {
            int c = col - 1024;
            kb[(((size_t)b * 16 + (c >> 6)) * 2048 + n) * 64 + (c & 63)] = (f16)v;
          }
        }
  } else {
    // v: blocked [bh][jblk][d][jin], packed f16x4 along n (jin)
    for (int mt = 0; mt < 4; mt++)
      for (int nt = 0; nt < 4; nt++) {
        int rb = m0 + wr + mt * 16 + quad * 4;
        int c  = n0 + wc + nt * 16 + l16 - 2048;
        int b = rb >> 11, n = rb & 2047;
        f16x4 pk = { (f16)acc[mt][nt][0], (f16)acc[mt][nt][1],
                     (f16)acc[mt][nt][2], (f16)acc[mt][nt][3] };
        size_t idx = (((size_t)(b * 16 + (c >> 6)) * 32 + (n >> 6)) * 64 + (c & 63)) * 64 + (n & 63);
        *(f16x4*)&vtb[idx] = pk;
      }
  }
}

// ---------------- GEMM2: out[M,1024] = A(M,1024)*Bt(1024,1024)^T + bo ----------------
__global__ __launch_bounds__(256) void gemm2(
    const f16* __restrict__ A, const f16* __restrict__ Bt,
    const float* __restrict__ bo, float* __restrict__ outf) {
  const int K = 1024;
  __shared__ f16 As[128 * 32];
  __shared__ f16 Bs[64 * 32];
  int tid = threadIdx.x;
  int wave = tid >> 6, lane = tid & 63, quad = lane >> 4, l16 = lane & 15;
  int m0 = blockIdx.y * 128, n0 = blockIdx.x * 64;
  int wr = (wave >> 1) * 64, wc = (wave & 1) * 32;

  f32x4 acc[4][2] = {};

  int gA = (((lane & 3) ^ ((lane >> 3) & 3))) * 8;
  const f16* Ag = A  + (size_t)(m0 + wave * 32 + (lane >> 2)) * K + gA;
  const f16* Bg = Bt + (size_t)(n0 + wave * 16 + (lane >> 2)) * K + gA;
  f16* Asw = As + wave * 1024;
  f16* Bsw = Bs + wave * 512;
  int rsz = (l16 >> 1) & 3;

  for (int k0 = 0; k0 < K; k0 += 32) {
    gll16(Ag + k0, Asw);
    gll16(Ag + (size_t)16 * K + k0, Asw + 512);
    gll16(Bg + k0, Bsw);
    __syncthreads();
    f16x8 af[4], bf[2];
    for (int mt = 0; mt < 4; mt++)
      af[mt] = *(const f16x8*)&As[(wr + mt * 16 + l16) * 32 + ((quad ^ rsz) << 3)];
    for (int nt = 0; nt < 2; nt++)
      bf[nt] = *(const f16x8*)&Bs[(wc + nt * 16 + l16) * 32 + ((quad ^ rsz) << 3)];
    for (int mt = 0; mt < 4; mt++)
      for (int nt = 0; nt < 2; nt++)
        acc[mt][nt] = __builtin_amdgcn_mfma_f32_16x16x32_f16(af[mt], bf[nt], acc[mt][nt], 0, 0, 0);
    __syncthreads();
  }

  for (int mt = 0; mt < 4; mt++)
    for (int nt = 0; nt < 2; nt++)
      for (int r = 0; r < 4; r++) {
        int row = m0 + wr + mt * 16 + quad * 4 + r;
        int col = n0 + wc + nt * 16 + l16;
        outf[(size_t)row * 1024 + col] = acc[mt][nt][r] + bo[col];
      }
}

// ---------------- fused causal attention: 16-row wave-tiles, 16 waves/CU ----------------
// Wave-parallelism is the binding constraint (r4 post-mortem): 128 m-tiles x 32 bh =
// 4096 waves = 16 waves/CU. Block = 64 q-rows (4 waves), grid 1024 = 4 blocks/CU.
// K/V LDS-staged per block (shared by 4 waves), XOR-swizzled; transposed-S formulation;
// XCD-pinned bh (r4: proven L2 locality win) -- same-CU blocks share one head's K/V.
// t(q,srem) mapping: every CU gets exactly sum(t+1)=66 j-iterations.
// gm (unmasked row-max) is only a softmax shift; cancels except via eps (<=3e-5).
__global__ __launch_bounds__(256, 4) void attn(
    const f16* __restrict__ qb, const f16* __restrict__ kb,
    const f16* __restrict__ vtb, f16* __restrict__ ob) {
  __shared__ f16 Ks[64 * 64];        // [j][d], swizzled
  __shared__ f16 Vs[64 * 64];        // [d][j], swizzled
  __shared__ f16 Ps[4][16 * 64];     // per-wave [i(16)][j(64)], swizzled
  int tid = threadIdx.x, wave = tid >> 6, lane = tid & 63, quad = lane >> 4, l16 = lane & 15;
  int l7 = l16 & 7;

  int bx = blockIdx.x;               // gridDim = 1024
  int q = bx >> 8, r = bx & 255;
  int xcd = r & 7, idx = r >> 3;
  int bh = xcd * 4 + (idx & 3);      // 4 heads per XCD -> 2MB K+V per XCD L2
  int srem = idx >> 2;               // 0..7
  int t;                             // 64-row tile 0..31; per-CU cost sum = 66 uniform
  if (q == 0)      t = srem;
  else if (q == 1) t = 15 - srem;
  else if (q == 2) t = 16 + srem;
  else             t = 31 - srem;
  int qi0 = t * 64;
  int b = bh >> 4, h = bh & 15;

  const f16* Q  = qb + (size_t)bh * 2048 * 64;
  const char* Kg = (const char*)(kb + (size_t)bh * 2048 * 64);
  const char* Vbase = (const char*)(vtb + (size_t)bh * 32 * 4096);
  int wq0 = qi0 + wave * 16;         // this wave's 16-row m-tile
  int i = wq0 + l16;                 // this lane's q-row

  f16x8 qf[2];
  for (int ks = 0; ks < 2; ks++)
    qf[ks] = *(const f16x8*)&Q[(size_t)(wq0 + l16) * 64 + ks * 32 + quad * 8];

  f32x4 acc[4] = {};
  float mrow = -1e30f, lrow = 0.f;

  // staging: lane covers 16B chunk (row jl, pos lane&7) holding global chunk (lane&7)^(jl&7)
  int sg = ((lane & 7) ^ ((lane >> 3) & 7)) * 16;
  int jl = wave * 16 + (lane >> 3);

  for (int j0 = 0; j0 < qi0 + 64; j0 += 64) {
    const char* kg = Kg + (size_t)j0 * 128;
    const char* vt = Vbase + (size_t)(j0 >> 6) * 8192;
    gll16(kg + (size_t)jl * 128 + sg,        (char*)Ks + wave * 2048);
    gll16(kg + (size_t)(jl + 8) * 128 + sg,  (char*)Ks + wave * 2048 + 1024);
    gll16(vt + (size_t)jl * 128 + sg,        (char*)Vs + wave * 2048);
    gll16(vt + (size_t)(jl + 8) * 128 + sg,  (char*)Vs + wave * 2048 + 1024);
    __syncthreads();

    if (j0 <= wq0 + 15) {            // wave-uniform: m-tile live for this j-block
      f16x8 kf[4][2], vf[4][2];
      for (int nt = 0; nt < 4; nt++)
        for (int ks = 0; ks < 2; ks++) {
          int pos = ((ks * 4 + quad) ^ l7) << 3;
          kf[nt][ks] = *(const f16x8*)&Ks[(nt * 16 + l16) * 64 + pos];
          vf[nt][ks] = *(const f16x8*)&Vs[(nt * 16 + l16) * 64 + pos];
        }

      // S^T tiles: lane = (j = j0+nt*16+quad*4+r, i = l16)
      f32x4 st[4];
      for (int nt = 0; nt < 4; nt++) {
        f32x4 z = {0.f, 0.f, 0.f, 0.f};
        z = __builtin_amdgcn_mfma_f32_16x16x32_f16(kf[nt][0], qf[0], z, 0, 0, 0);
        z = __builtin_amdgcn_mfma_f32_16x16x32_f16(kf[nt][1], qf[1], z, 0, 0, 0);
        st[nt] = z;
      }
      if (j0 + 63 > wq0) {           // partial block: causal mask
        for (int nt = 0; nt < 4; nt++) {
          int jc = j0 + nt * 16 + quad * 4;
          for (int rr = 0; rr < 4; rr++)
            st[nt][rr] = (jc + rr <= i) ? st[nt][rr] : -1e30f;
        }
      }
      // row max: reg tree + 2 cross-quad shuffles
      float v = fmaxf(fmaxf(fmaxf(st[0][0], st[0][1]), fmaxf(st[0][2], st[0][3])),
                      fmaxf(fmaxf(st[1][0], st[1][1]), fmaxf(st[1][2], st[1][3])));
      v = fmaxf(v, fmaxf(fmaxf(fmaxf(st[2][0], st[2][1]), fmaxf(st[2][2], st[2][3])),
                         fmaxf(fmaxf(st[3][0], st[3][1]), fmaxf(st[3][2], st[3][3]))));
      v = fmaxf(v, __shfl_xor(v, 16));
      v = fmaxf(v, __shfl_xor(v, 32));
      float mold = mrow;
      float mn = fmaxf(mold, v);
      mrow = mn;
      if (__any(mn > mold)) {        // skip rescale when no row got a new max
        float al = __builtin_amdgcn_exp2f(mold - mn);
        lrow *= al;
        for (int nt = 0; nt < 4; nt++)
          for (int rr = 0; rr < 4; rr++) acc[nt][rr] *= al;
      }
      // p = 2^(s-m) (masked entries underflow to 0); packed swizzled write to Ps[i][j]
      float psum = 0.f;
      for (int nt = 0; nt < 4; nt++) {
        f16x4 pk;
        for (int rr = 0; rr < 4; rr++) {
          float p = __builtin_amdgcn_exp2f(st[nt][rr] - mn);
          psum += p;
          pk[rr] = (f16)p;
        }
        int pos = (nt * 2 + (quad >> 1)) ^ l7;
        *(f16x4*)((char*)&Ps[wave][0] + l16 * 128 + pos * 16 + (quad & 1) * 8) = pk;
      }
      psum += __shfl_xor(psum, 16);
      psum += __shfl_xor(psum, 32);
      lrow += psum;

      // O^T += V^T P^T
      for (int ks = 0; ks < 2; ks++) {
        f16x8 pf = *(const f16x8*)((char*)&Ps[wave][0] + l16 * 128 + (((ks * 4 + quad) ^ l7) * 16));
        for (int nt = 0; nt < 4; nt++)
          acc[nt] = __builtin_amdgcn_mfma_f32_16x16x32_f16(vf[nt][ks], pf, acc[nt], 0, 0, 0);
      }
    }
    __syncthreads();
  }

  // out = acc / (l + eps); acc lane = (d = nt*16+quad*4+r, i = l16) -> f16x4 along d
  float inv = 1.f / (lrow + 1e-8f);
  int n = wq0 + l16;
  for (int nt = 0; nt < 4; nt++) {
    f16x4 o = { (f16)(acc[nt][0] * inv), (f16)(acc[nt][1] * inv),
                (f16)(acc[nt][2] * inv), (f16)(acc[nt][3] * inv) };
    *(f16x4*)&ob[((size_t)b * 2048 + n) * 1024 + h * 64 + nt * 16 + quad * 4] = o;
  }
}

extern "C" void kernel_launch(void* const* d_in, const int* in_sizes, int n_in,
                              void* d_out, int out_size, void* d_ws, size_t ws_size,
                              hipStream_t stream) {
  const float* x   = (const float*)d_in[0];   // (2,2048,1024)
  const float* Wq  = (const float*)d_in[1];   // (1024,1024)
  const float* Wkv = (const float*)d_in[2];   // (1024,2048)
  const float* Wo  = (const float*)d_in[3];   // (1024,1024)
  const float* bo  = (const float*)d_in[4];   // (1024,)
  float* out = (float*)d_out;                 // (2,2048,1024) f32

  char* ws = (char*)d_ws;
  f16* xb    = (f16*)ws;  ws += (size_t)4096 * 1024 * 2;
  f16* WqkvT = (f16*)ws;  ws += (size_t)3072 * 1024 * 2;
  f16* WoT   = (f16*)ws;  ws += (size_t)1024 * 1024 * 2;
  f16* qb    = (f16*)ws;  ws += (size_t)32 * 2048 * 64 * 2;
  f16* kb    = (f16*)ws;  ws += (size_t)32 * 2048 * 64 * 2;
  f16* vtb   = (f16*)ws;  ws += (size_t)32 * 64 * 2048 * 2;
  f16* ob    = xb;  // xb dead after GEMM1; reuse

  prep<<<dim3(64, 32, 4), dim3(32, 8), 0, stream>>>(Wq, Wkv, Wo, x, WqkvT, WoT, xb);
  gemm1<<<dim3(24, 32), 256, 0, stream>>>(xb, WqkvT, qb, kb, vtb);
  attn<<<dim3(1024), 256, 0, stream>>>(qb, kb, vtb, ob);
  gemm2<<<dim3(16, 32), 256, 0, stream>>>(ob, WoT, bo, out);
}